// Round 12
// baseline (377.113 us; speedup 1.0000x reference)
//
#include <hip/hip_runtime.h>
#include <hip/hip_bf16.h>

// B=2048, T=32, V=1024, D=256
// idx[b][t] = argmin_v (c2[t][v] - 2*x[b][t].c[t][v]);  embed = gathered codebook rows.
// R12: finish-overflow fix. Ledger across R5/R9/R10/R11: total - main = ~140us
// constant => finish ~100-115us (never in top-5). Theory: CAP=32 overflow ->
// 16-lane group rescans all 1024 codes serially (~150us), deterministic for
// this dataset. Fix: CAP=64 (overflow ~never; main LDS 41.3KB still 3/CU),
// 4-way-ILP fallback (worst ~25us), 2-way-ILP candidate loop. Main reverted to
// banked R10 config (depth-2 prefetch + R8 determinism barrier) unchanged.
// R11 lesson: depth-4 reg ring spilled (WRITE 11->85MB) - reverted.

#define B_ 2048
#define T_ 32
#define V_ 1024
#define D_ 256
#define BT 64
#define VTILE 256
#define NVT 4          // V_/VTILE
#define CAP 64
#define MARGIN 8.0f

typedef __attribute__((ext_vector_type(8))) short short8;   // 8 bf16 = 4 VGPR
typedef __attribute__((ext_vector_type(4))) float f32x4;

__device__ __forceinline__ unsigned short f2bf(float f) {
    unsigned u = __builtin_bit_cast(unsigned, f);
    unsigned r = u + 0x7FFFu + ((u >> 16) & 1u);
    return (unsigned short)(r >> 16);
}

__device__ __forceinline__ short8 pack8(float4 a, float4 b) {
    short8 r;
    r[0] = (short)f2bf(a.x); r[1] = (short)f2bf(a.y);
    r[2] = (short)f2bf(a.z); r[3] = (short)f2bf(a.w);
    r[4] = (short)f2bf(b.x); r[5] = (short)f2bf(b.y);
    r[6] = (short)f2bf(b.z); r[7] = (short)f2bf(b.w);
    return r;
}

// ---- prep: c2 exact fp32 + codebook -> bf16; 4 rows/wave for ILP
__global__ void prep_kernel(const float* __restrict__ cb, float* __restrict__ c2,
                            unsigned short* __restrict__ cbb) {
    const int wave = threadIdx.x >> 6, lane = threadIdx.x & 63;
    const int row0 = blockIdx.x * 16 + wave * 4;
    float4 v4[4];
    float s[4];
    #pragma unroll
    for (int j = 0; j < 4; ++j) {
        v4[j] = *(const float4*)(cb + (size_t)(row0 + j) * D_ + lane * 4);
        s[j] = v4[j].x * v4[j].x + v4[j].y * v4[j].y
             + v4[j].z * v4[j].z + v4[j].w * v4[j].w;
    }
    #pragma unroll
    for (int off = 32; off; off >>= 1) {
        #pragma unroll
        for (int j = 0; j < 4; ++j) s[j] += __shfl_down(s[j], off, 64);
    }
    if (lane == 0) {
        #pragma unroll
        for (int j = 0; j < 4; ++j) c2[row0 + j] = s[j];
    }
    #pragma unroll
    for (int j = 0; j < 4; ++j) {
        ushort4 b4;
        b4.x = f2bf(v4[j].x); b4.y = f2bf(v4[j].y);
        b4.z = f2bf(v4[j].z); b4.w = f2bf(v4[j].w);
        *(ushort4*)(cbb + (size_t)(row0 + j) * D_ + lane * 4) = b4;
    }
}

// ---- fallback prep when ws too small: c2 only
__global__ void c2_kernel(const float* __restrict__ cb, float* __restrict__ c2) {
    const int row = blockIdx.x * 4 + (threadIdx.x >> 6);
    const int lane = threadIdx.x & 63;
    const float4 v = ((const float4*)(cb + (size_t)row * D_))[lane];
    float s = v.x * v.x + v.y * v.y + v.z * v.z + v.w * v.w;
    #pragma unroll
    for (int off = 32; off; off >>= 1) s += __shfl_down(s, off, 64);
    if (lane == 0) c2[row] = s;
}

// ---------------- main: MFMA sweep + candidate collect ----------------
template<int USE_BF>
__global__ __launch_bounds__(256, 3)
void main_kernel(const float* __restrict__ x, const float* __restrict__ cb,
                 const float* __restrict__ c2, const unsigned short* __restrict__ cbb,
                 float* __restrict__ out) {
    const int t  = blockIdx.x;
    const int b0 = blockIdx.y * BT;

    __shared__ short8 A_lds[BT * 32];          // 64 rows x 32 granules, XOR(r&15)
    __shared__ float  minPart4[BT][4];         // per-row per-wave running min
    __shared__ unsigned rowCnt[BT];
    __shared__ unsigned short rowCand[BT * CAP];

    const int tid = threadIdx.x;
    const int w = tid >> 6, lane = tid & 63;
    const int q = lane >> 4, ln = lane & 15;

    if (tid < BT) rowCnt[tid] = 0;
    ((float*)minPart4)[tid] = 3.4e38f;         // 256 = BT*4 exactly

    #pragma unroll
    for (int i = 0; i < 8; ++i) {
        int gid = i * 256 + tid, r = gid >> 5, g = gid & 31;
        const float4* src = (const float4*)(x + (((size_t)(b0 + r)) * T_ + t) * D_ + g * 8);
        A_lds[r * 32 + (g ^ (r & 15))] = pack8(src[0], src[1]);
    }

    const unsigned short* bb = cbb + ((size_t)t * V_ + w * 64 + ln) * D_ + q * 8;
    const float*          fb = cb  + ((size_t)t * V_ + w * 64 + ln) * D_ + q * 8;

    auto loadB = [&](int vt, int kc, short8 (&dst)[4]) {
        #pragma unroll
        for (int nt = 0; nt < 4; ++nt) {
            const int off = (vt * VTILE + nt * 16) * D_ + kc * 32;
            if constexpr (USE_BF) {
                dst[nt] = *(const short8*)(bb + off);
            } else {
                const float4* s = (const float4*)(fb + off);
                dst[nt] = pack8(s[0], s[1]);
            }
        }
    };

    short8 bufs0[4], bufs1[4];
    loadB(0, 0, bufs0);
    __syncthreads();                 // A_lds writes + inits visible

    for (int vt = 0; vt < NVT; ++vt) {
        f32x4 acc[4][4];
        #pragma unroll
        for (int mt = 0; mt < 4; ++mt)
            #pragma unroll
            for (int nt = 0; nt < 4; ++nt) acc[mt][nt] = (f32x4){0.f, 0.f, 0.f, 0.f};

        #pragma unroll
        for (int kc = 0; kc < 8; ++kc) {
            if (!(vt == NVT - 1 && kc == 7)) {
                if (kc & 1) loadB(vt + (kc == 7), (kc + 1) & 7, bufs0);
                else        loadB(vt,             kc + 1,       bufs1);
            }
            short8 af[4];
            #pragma unroll
            for (int mt = 0; mt < 4; ++mt)
                af[mt] = A_lds[(mt * 16 + ln) * 32 + ((kc * 4 + q) ^ ln)];
            #pragma unroll
            for (int mt = 0; mt < 4; ++mt)
                #pragma unroll
                for (int nt = 0; nt < 4; ++nt)
                    acc[mt][nt] = __builtin_amdgcn_mfma_f32_16x16x32_bf16(
                        af[mt], (kc & 1) ? bufs1[nt] : bufs0[nt], acc[mt][nt], 0, 0, 0);
        }

        const float* c2p = c2 + t * V_ + vt * VTILE + w * 64 + ln;
        float cc[4];
        #pragma unroll
        for (int nt = 0; nt < 4; ++nt) cc[nt] = c2p[nt * 16];

        #pragma unroll
        for (int mt = 0; mt < 4; ++mt)
            #pragma unroll
            for (int i = 0; i < 4; ++i) {
                float mn = 3.4e38f;
                #pragma unroll
                for (int nt = 0; nt < 4; ++nt)
                    mn = fminf(mn, fmaf(-2.0f, acc[mt][nt][i], cc[nt]));
                mn = fminf(mn, __shfl_xor(mn, 1, 64));
                mn = fminf(mn, __shfl_xor(mn, 2, 64));
                mn = fminf(mn, __shfl_xor(mn, 4, 64));
                mn = fminf(mn, __shfl_xor(mn, 8, 64));
                if (ln == 0) {
                    const int r = mt * 16 + q * 4 + i;
                    minPart4[r][w] = fminf(minPart4[r][w], mn);
                }
            }
        __syncthreads();   // this vt's 4-wave mins visible

        #pragma unroll
        for (int mt = 0; mt < 4; ++mt)
            #pragma unroll
            for (int i = 0; i < 4; ++i) {
                const int r = mt * 16 + q * 4 + i;
                const float4 mp = *(const float4*)minPart4[r];
                const float thr = fminf(fminf(mp.x, mp.y), fminf(mp.z, mp.w)) + MARGIN;
                #pragma unroll
                for (int nt = 0; nt < 4; ++nt) {
                    float s = fmaf(-2.0f, acc[mt][nt][i], cc[nt]);
                    if (s < thr) {
                        unsigned pos = atomicAdd(&rowCnt[r], 1u);
                        if (pos < CAP)
                            rowCand[r * CAP + pos] =
                                (unsigned short)(vt * VTILE + w * 64 + nt * 16 + ln);
                    }
                }
            }
        // DETERMINISM BARRIER (R8 fix): collect(vt) must see exactly mins
        // through vt; without this a fast wave's next-vt update races.
        __syncthreads();
    }

    // ---- dump cnt + cand list into the row's own embed slot (finish overwrites)
    if (tid < BT) {
        const int r = tid;
        unsigned* slot = (unsigned*)(out + (((size_t)(b0 + r)) * T_ + t) * D_);
        slot[0] = rowCnt[r];
        const unsigned short* rc = &rowCand[r * CAP];
        #pragma unroll
        for (int k = 0; k < CAP / 2; ++k)
            slot[1 + k] = (unsigned)rc[2 * k] | ((unsigned)rc[2 * k + 1] << 16);
    }
}

// ---------------- finish: exact fp32 rescore + idx + gather ----------------
__global__ __launch_bounds__(256, 8)
void finish_kernel(const float* __restrict__ x, const float* __restrict__ cb,
                   const float* __restrict__ c2, float* __restrict__ out) {
    const int t = blockIdx.x;
    const int b = blockIdx.y * 16 + (threadIdx.x >> 4);   // one row per 16-lane group
    const int l16 = threadIdx.x & 15;

    float* slot = out + ((size_t)b * T_ + t) * D_;
    const unsigned cnt = ((const unsigned*)slot)[0];

    const float* xp = x + ((size_t)b * T_ + t) * D_ + l16 * 16;
    float4 xr[4];
    #pragma unroll
    for (int k = 0; k < 4; ++k) xr[k] = ((const float4*)xp)[k];

    const float* cbt = cb + (size_t)t * V_ * D_ + l16 * 16;
    const float* c2t = c2 + t * V_;

    auto dot16 = [&](int v) {   // partial dot over this lane's 16 elems
        const float* cr = cbt + (size_t)v * D_;
        float d = 0.f;
        #pragma unroll
        for (int k = 0; k < 4; ++k) {
            float4 bv = ((const float4*)cr)[k];
            d = fmaf(xr[k].x, bv.x, d); d = fmaf(xr[k].y, bv.y, d);
            d = fmaf(xr[k].z, bv.z, d); d = fmaf(xr[k].w, bv.w, d);
        }
        return d;
    };
    auto reduce16 = [&](float d) {
        d += __shfl_xor(d, 1, 64);
        d += __shfl_xor(d, 2, 64);
        d += __shfl_xor(d, 4, 64);
        d += __shfl_xor(d, 8, 64);
        return d;
    };
    unsigned long long best = ~0ULL;
    auto merge = [&](float dot, int v) {
        float sc = fmaf(-2.0f, dot, c2t[v]);
        unsigned u = __builtin_bit_cast(unsigned, sc);
        u = (u & 0x80000000u) ? ~u : (u | 0x80000000u);   // sortable fp32
        unsigned long long e = ((unsigned long long)u << 32) | (unsigned)v;
        if (e < best) best = e;
    };

    if (cnt <= CAP) {
        unsigned c = 0;
        for (; c + 2 <= cnt; c += 2) {          // 2-way ILP (pairs are one uint)
            unsigned pr = ((const unsigned*)slot)[1 + (c >> 1)];
            const int v0 = (int)(pr & 0xffffu), v1 = (int)(pr >> 16);
            float d0 = dot16(v0), d1 = dot16(v1);
            d0 = reduce16(d0); d1 = reduce16(d1);
            merge(d0, v0); merge(d1, v1);
        }
        if (c < cnt) {
            unsigned pr = ((const unsigned*)slot)[1 + (c >> 1)];
            const int v0 = (int)(pr & 0xffffu);
            merge(reduce16(dot16(v0)), v0);
        }
    } else {
        for (int v = 0; v < V_; v += 4) {       // overflow fallback, 4-way ILP
            float d0 = dot16(v),     d1 = dot16(v + 1);
            float d2 = dot16(v + 2), d3 = dot16(v + 3);
            d0 = reduce16(d0); d1 = reduce16(d1);
            d2 = reduce16(d2); d3 = reduce16(d3);
            merge(d0, v); merge(d1, v + 1); merge(d2, v + 2); merge(d3, v + 3);
        }
    }

    // all 16 lanes hold identical best (uniform loop + full 16-lane reduce)
    const int idx = (int)(best & 1023u);
    if (l16 == 0) out[(size_t)B_ * T_ * D_ + (size_t)b * T_ + t] = (float)idx;

    // gather: overwrite slot with codebook row (reads of slot are done above)
    const float* cr = cb + ((size_t)t * V_ + idx) * D_;
    #pragma unroll
    for (int k = 0; k < 4; ++k)
        *(float4*)(slot + k * 64 + l16 * 4) = *(const float4*)(cr + k * 64 + l16 * 4);
}

extern "C" void kernel_launch(void* const* d_in, const int* in_sizes, int n_in,
                              void* d_out, int out_size, void* d_ws, size_t ws_size,
                              hipStream_t stream) {
    const float* x  = (const float*)d_in[0];   // (B,T,D)
    const float* cb = (const float*)d_in[1];   // (T,V,D)
    float* out = (float*)d_out;                // embed fp32 ++ idx (as float)
    float* c2  = (float*)d_ws;                 // 32768 floats = 128 KB
    unsigned short* cbb = (unsigned short*)((char*)d_ws + 131072);  // 16 MB bf16 codebook
    const size_t NEED = 131072 + (size_t)T_ * V_ * D_ * 2;
    const int use_bf = (ws_size >= NEED) ? 1 : 0;

    if (use_bf) {
        prep_kernel<<<dim3(T_ * V_ / 16), 256, 0, stream>>>(cb, c2, cbb);
        main_kernel<1><<<dim3(T_, B_ / BT), 256, 0, stream>>>(x, cb, c2, cbb, out);
    } else {
        c2_kernel<<<dim3(T_ * V_ / 4), 256, 0, stream>>>(cb, c2);
        main_kernel<0><<<dim3(T_, B_ / BT), 256, 0, stream>>>(x, cb, c2, cbb, out);
    }
    finish_kernel<<<dim3(T_, B_ / 16), 256, 0, stream>>>(x, cb, c2, out);
}

// Round 13
// 275.704 us; speedup vs baseline: 1.3678x; 1.3678x over previous
//
#include <hip/hip_runtime.h>
#include <hip/hip_bf16.h>

// B=2048, T=32, V=1024, D=256
// idx[b][t] = argmin_v (c2[t][v] - 2*x[b][t].c[t][v]);  embed = gathered codebook rows.
// R13: revert R12's two regressions + fix finish's register cliff.
// R12 evidence: CAP=64 -> rowCand 128B stride -> bank conflicts 187K->752K,
// main 132->147. finish at __launch_bounds__(256,8) = 64-VGPR cap; 4-way
// fallback needs ~100 VGPR -> whole-kernel spills -> finish +90us (ledger
// 142->230). Fix: CAP=32 (main back to banked config), finish at (256,4)
// = 128-VGPR cap with the ILP loops kept. Pre-commit: finish spill-bound ->
// total ~225-245; finish intrinsic ~105 -> total ~270, R14 targets its
// memory path (136MB HBM = 21us floor).

#define B_ 2048
#define T_ 32
#define V_ 1024
#define D_ 256
#define BT 64
#define VTILE 256
#define NVT 4          // V_/VTILE
#define CAP 32
#define MARGIN 8.0f

typedef __attribute__((ext_vector_type(8))) short short8;   // 8 bf16 = 4 VGPR
typedef __attribute__((ext_vector_type(4))) float f32x4;

__device__ __forceinline__ unsigned short f2bf(float f) {
    unsigned u = __builtin_bit_cast(unsigned, f);
    unsigned r = u + 0x7FFFu + ((u >> 16) & 1u);
    return (unsigned short)(r >> 16);
}

__device__ __forceinline__ short8 pack8(float4 a, float4 b) {
    short8 r;
    r[0] = (short)f2bf(a.x); r[1] = (short)f2bf(a.y);
    r[2] = (short)f2bf(a.z); r[3] = (short)f2bf(a.w);
    r[4] = (short)f2bf(b.x); r[5] = (short)f2bf(b.y);
    r[6] = (short)f2bf(b.z); r[7] = (short)f2bf(b.w);
    return r;
}

// ---- prep: c2 exact fp32 + codebook -> bf16; 4 rows/wave for ILP
__global__ void prep_kernel(const float* __restrict__ cb, float* __restrict__ c2,
                            unsigned short* __restrict__ cbb) {
    const int wave = threadIdx.x >> 6, lane = threadIdx.x & 63;
    const int row0 = blockIdx.x * 16 + wave * 4;
    float4 v4[4];
    float s[4];
    #pragma unroll
    for (int j = 0; j < 4; ++j) {
        v4[j] = *(const float4*)(cb + (size_t)(row0 + j) * D_ + lane * 4);
        s[j] = v4[j].x * v4[j].x + v4[j].y * v4[j].y
             + v4[j].z * v4[j].z + v4[j].w * v4[j].w;
    }
    #pragma unroll
    for (int off = 32; off; off >>= 1) {
        #pragma unroll
        for (int j = 0; j < 4; ++j) s[j] += __shfl_down(s[j], off, 64);
    }
    if (lane == 0) {
        #pragma unroll
        for (int j = 0; j < 4; ++j) c2[row0 + j] = s[j];
    }
    #pragma unroll
    for (int j = 0; j < 4; ++j) {
        ushort4 b4;
        b4.x = f2bf(v4[j].x); b4.y = f2bf(v4[j].y);
        b4.z = f2bf(v4[j].z); b4.w = f2bf(v4[j].w);
        *(ushort4*)(cbb + (size_t)(row0 + j) * D_ + lane * 4) = b4;
    }
}

// ---- fallback prep when ws too small: c2 only
__global__ void c2_kernel(const float* __restrict__ cb, float* __restrict__ c2) {
    const int row = blockIdx.x * 4 + (threadIdx.x >> 6);
    const int lane = threadIdx.x & 63;
    const float4 v = ((const float4*)(cb + (size_t)row * D_))[lane];
    float s = v.x * v.x + v.y * v.y + v.z * v.z + v.w * v.w;
    #pragma unroll
    for (int off = 32; off; off >>= 1) s += __shfl_down(s, off, 64);
    if (lane == 0) c2[row] = s;
}

// ---------------- main: MFMA sweep + candidate collect ----------------
template<int USE_BF>
__global__ __launch_bounds__(256, 3)
void main_kernel(const float* __restrict__ x, const float* __restrict__ cb,
                 const float* __restrict__ c2, const unsigned short* __restrict__ cbb,
                 float* __restrict__ out) {
    const int t  = blockIdx.x;
    const int b0 = blockIdx.y * BT;

    __shared__ short8 A_lds[BT * 32];          // 64 rows x 32 granules, XOR(r&15)
    __shared__ float  minPart4[BT][4];         // per-row per-wave running min
    __shared__ unsigned rowCnt[BT];
    __shared__ unsigned short rowCand[BT * CAP];

    const int tid = threadIdx.x;
    const int w = tid >> 6, lane = tid & 63;
    const int q = lane >> 4, ln = lane & 15;

    if (tid < BT) rowCnt[tid] = 0;
    ((float*)minPart4)[tid] = 3.4e38f;         // 256 = BT*4 exactly

    #pragma unroll
    for (int i = 0; i < 8; ++i) {
        int gid = i * 256 + tid, r = gid >> 5, g = gid & 31;
        const float4* src = (const float4*)(x + (((size_t)(b0 + r)) * T_ + t) * D_ + g * 8);
        A_lds[r * 32 + (g ^ (r & 15))] = pack8(src[0], src[1]);
    }

    const unsigned short* bb = cbb + ((size_t)t * V_ + w * 64 + ln) * D_ + q * 8;
    const float*          fb = cb  + ((size_t)t * V_ + w * 64 + ln) * D_ + q * 8;

    auto loadB = [&](int vt, int kc, short8 (&dst)[4]) {
        #pragma unroll
        for (int nt = 0; nt < 4; ++nt) {
            const int off = (vt * VTILE + nt * 16) * D_ + kc * 32;
            if constexpr (USE_BF) {
                dst[nt] = *(const short8*)(bb + off);
            } else {
                const float4* s = (const float4*)(fb + off);
                dst[nt] = pack8(s[0], s[1]);
            }
        }
    };

    short8 bufs0[4], bufs1[4];
    loadB(0, 0, bufs0);
    __syncthreads();                 // A_lds writes + inits visible

    for (int vt = 0; vt < NVT; ++vt) {
        f32x4 acc[4][4];
        #pragma unroll
        for (int mt = 0; mt < 4; ++mt)
            #pragma unroll
            for (int nt = 0; nt < 4; ++nt) acc[mt][nt] = (f32x4){0.f, 0.f, 0.f, 0.f};

        #pragma unroll
        for (int kc = 0; kc < 8; ++kc) {
            if (!(vt == NVT - 1 && kc == 7)) {
                if (kc & 1) loadB(vt + (kc == 7), (kc + 1) & 7, bufs0);
                else        loadB(vt,             kc + 1,       bufs1);
            }
            short8 af[4];
            #pragma unroll
            for (int mt = 0; mt < 4; ++mt)
                af[mt] = A_lds[(mt * 16 + ln) * 32 + ((kc * 4 + q) ^ ln)];
            #pragma unroll
            for (int mt = 0; mt < 4; ++mt)
                #pragma unroll
                for (int nt = 0; nt < 4; ++nt)
                    acc[mt][nt] = __builtin_amdgcn_mfma_f32_16x16x32_bf16(
                        af[mt], (kc & 1) ? bufs1[nt] : bufs0[nt], acc[mt][nt], 0, 0, 0);
        }

        const float* c2p = c2 + t * V_ + vt * VTILE + w * 64 + ln;
        float cc[4];
        #pragma unroll
        for (int nt = 0; nt < 4; ++nt) cc[nt] = c2p[nt * 16];

        #pragma unroll
        for (int mt = 0; mt < 4; ++mt)
            #pragma unroll
            for (int i = 0; i < 4; ++i) {
                float mn = 3.4e38f;
                #pragma unroll
                for (int nt = 0; nt < 4; ++nt)
                    mn = fminf(mn, fmaf(-2.0f, acc[mt][nt][i], cc[nt]));
                mn = fminf(mn, __shfl_xor(mn, 1, 64));
                mn = fminf(mn, __shfl_xor(mn, 2, 64));
                mn = fminf(mn, __shfl_xor(mn, 4, 64));
                mn = fminf(mn, __shfl_xor(mn, 8, 64));
                if (ln == 0) {
                    const int r = mt * 16 + q * 4 + i;
                    minPart4[r][w] = fminf(minPart4[r][w], mn);
                }
            }
        __syncthreads();   // this vt's 4-wave mins visible

        #pragma unroll
        for (int mt = 0; mt < 4; ++mt)
            #pragma unroll
            for (int i = 0; i < 4; ++i) {
                const int r = mt * 16 + q * 4 + i;
                const float4 mp = *(const float4*)minPart4[r];
                const float thr = fminf(fminf(mp.x, mp.y), fminf(mp.z, mp.w)) + MARGIN;
                #pragma unroll
                for (int nt = 0; nt < 4; ++nt) {
                    float s = fmaf(-2.0f, acc[mt][nt][i], cc[nt]);
                    if (s < thr) {
                        unsigned pos = atomicAdd(&rowCnt[r], 1u);
                        if (pos < CAP)
                            rowCand[r * CAP + pos] =
                                (unsigned short)(vt * VTILE + w * 64 + nt * 16 + ln);
                    }
                }
            }
        // DETERMINISM BARRIER (R8 fix): collect(vt) must see exactly mins
        // through vt; without this a fast wave's next-vt update races.
        __syncthreads();
    }

    // ---- dump cnt + cand list into the row's own embed slot (finish overwrites)
    if (tid < BT) {
        const int r = tid;
        unsigned* slot = (unsigned*)(out + (((size_t)(b0 + r)) * T_ + t) * D_);
        slot[0] = rowCnt[r];
        const unsigned short* rc = &rowCand[r * CAP];
        #pragma unroll
        for (int k = 0; k < CAP / 2; ++k)
            slot[1 + k] = (unsigned)rc[2 * k] | ((unsigned)rc[2 * k + 1] << 16);
    }
}

// ---------------- finish: exact fp32 rescore + idx + gather ----------------
// (256,4): 128-VGPR cap. At (256,8) the 64-VGPR cap forced whole-kernel
// spills once the 4-way fallback (~100 VGPR live) was added (R12 regression).
__global__ __launch_bounds__(256, 4)
void finish_kernel(const float* __restrict__ x, const float* __restrict__ cb,
                   const float* __restrict__ c2, float* __restrict__ out) {
    const int t = blockIdx.x;
    const int b = blockIdx.y * 16 + (threadIdx.x >> 4);   // one row per 16-lane group
    const int l16 = threadIdx.x & 15;

    float* slot = out + ((size_t)b * T_ + t) * D_;
    const unsigned cnt = ((const unsigned*)slot)[0];

    const float* xp = x + ((size_t)b * T_ + t) * D_ + l16 * 16;
    float4 xr[4];
    #pragma unroll
    for (int k = 0; k < 4; ++k) xr[k] = ((const float4*)xp)[k];

    const float* cbt = cb + (size_t)t * V_ * D_ + l16 * 16;
    const float* c2t = c2 + t * V_;

    auto dot16 = [&](int v) {   // partial dot over this lane's 16 elems
        const float* cr = cbt + (size_t)v * D_;
        float d = 0.f;
        #pragma unroll
        for (int k = 0; k < 4; ++k) {
            float4 bv = ((const float4*)cr)[k];
            d = fmaf(xr[k].x, bv.x, d); d = fmaf(xr[k].y, bv.y, d);
            d = fmaf(xr[k].z, bv.z, d); d = fmaf(xr[k].w, bv.w, d);
        }
        return d;
    };
    auto reduce16 = [&](float d) {
        d += __shfl_xor(d, 1, 64);
        d += __shfl_xor(d, 2, 64);
        d += __shfl_xor(d, 4, 64);
        d += __shfl_xor(d, 8, 64);
        return d;
    };
    unsigned long long best = ~0ULL;
    auto merge = [&](float dot, int v) {
        float sc = fmaf(-2.0f, dot, c2t[v]);
        unsigned u = __builtin_bit_cast(unsigned, sc);
        u = (u & 0x80000000u) ? ~u : (u | 0x80000000u);   // sortable fp32
        unsigned long long e = ((unsigned long long)u << 32) | (unsigned)v;
        if (e < best) best = e;
    };

    if (cnt <= CAP) {
        unsigned c = 0;
        for (; c + 2 <= cnt; c += 2) {          // 2-way ILP (pairs are one uint)
            unsigned pr = ((const unsigned*)slot)[1 + (c >> 1)];
            const int v0 = (int)(pr & 0xffffu), v1 = (int)(pr >> 16);
            float d0 = dot16(v0), d1 = dot16(v1);
            d0 = reduce16(d0); d1 = reduce16(d1);
            merge(d0, v0); merge(d1, v1);
        }
        if (c < cnt) {
            unsigned pr = ((const unsigned*)slot)[1 + (c >> 1)];
            const int v0 = (int)(pr & 0xffffu);
            merge(reduce16(dot16(v0)), v0);
        }
    } else {
        for (int v = 0; v < V_; v += 4) {       // overflow fallback, 4-way ILP
            float d0 = dot16(v),     d1 = dot16(v + 1);
            float d2 = dot16(v + 2), d3 = dot16(v + 3);
            d0 = reduce16(d0); d1 = reduce16(d1);
            d2 = reduce16(d2); d3 = reduce16(d3);
            merge(d0, v); merge(d1, v + 1); merge(d2, v + 2); merge(d3, v + 3);
        }
    }

    // all 16 lanes hold identical best (uniform loop + full 16-lane reduce)
    const int idx = (int)(best & 1023u);
    if (l16 == 0) out[(size_t)B_ * T_ * D_ + (size_t)b * T_ + t] = (float)idx;

    // gather: overwrite slot with codebook row (reads of slot are done above)
    const float* cr = cb + ((size_t)t * V_ + idx) * D_;
    #pragma unroll
    for (int k = 0; k < 4; ++k)
        *(float4*)(slot + k * 64 + l16 * 4) = *(const float4*)(cr + k * 64 + l16 * 4);
}

extern "C" void kernel_launch(void* const* d_in, const int* in_sizes, int n_in,
                              void* d_out, int out_size, void* d_ws, size_t ws_size,
                              hipStream_t stream) {
    const float* x  = (const float*)d_in[0];   // (B,T,D)
    const float* cb = (const float*)d_in[1];   // (T,V,D)
    float* out = (float*)d_out;                // embed fp32 ++ idx (as float)
    float* c2  = (float*)d_ws;                 // 32768 floats = 128 KB
    unsigned short* cbb = (unsigned short*)((char*)d_ws + 131072);  // 16 MB bf16 codebook
    const size_t NEED = 131072 + (size_t)T_ * V_ * D_ * 2;
    const int use_bf = (ws_size >= NEED) ? 1 : 0;

    if (use_bf) {
        prep_kernel<<<dim3(T_ * V_ / 16), 256, 0, stream>>>(cb, c2, cbb);
        main_kernel<1><<<dim3(T_, B_ / BT), 256, 0, stream>>>(x, cb, c2, cbb, out);
    } else {
        c2_kernel<<<dim3(T_ * V_ / 4), 256, 0, stream>>>(cb, c2);
        main_kernel<0><<<dim3(T_, B_ / BT), 256, 0, stream>>>(x, cb, c2, cbb, out);
    }
    finish_kernel<<<dim3(T_, B_ / 16), 256, 0, stream>>>(x, cb, c2, out);
}

// Round 14
// 262.883 us; speedup vs baseline: 1.4345x; 1.0488x over previous
//
#include <hip/hip_runtime.h>
#include <hip/hip_bf16.h>

// B=2048, T=32, V=1024, D=256
// idx[b][t] = argmin_v (c2[t][v] - 2*x[b][t].c[t][v]);  embed = gathered codebook rows.
// R14: R11's depth-4 prefetch ring, deconfounded. R11 ran the ring at
// __launch_bounds__(256,3): compiler kept VGPR=84 and SPILLED the ring
// (WRITE 11->85MB) -> latency theory never tested. This round: identical ring
// at (256,2) (reg cap 256 -> ring lives in registers; occupancy 3->2 blocks/CU,
// shown ~free in R2/R8). Gate: WRITE_SIZE ~11MB. If latency-bound: main
// 136 -> 60-85us. If clean-but-unchanged: 2000cy/step is a platform wall.
// Ring slots (vt*8+kc)%4 == kc%4: all compile-time (rule #20 safe).
// prep/finish byte-identical to R13.

#define B_ 2048
#define T_ 32
#define V_ 1024
#define D_ 256
#define BT 64
#define VTILE 256
#define NVT 4          // V_/VTILE
#define CAP 32
#define MARGIN 8.0f

typedef __attribute__((ext_vector_type(8))) short short8;   // 8 bf16 = 4 VGPR
typedef __attribute__((ext_vector_type(4))) float f32x4;

__device__ __forceinline__ unsigned short f2bf(float f) {
    unsigned u = __builtin_bit_cast(unsigned, f);
    unsigned r = u + 0x7FFFu + ((u >> 16) & 1u);
    return (unsigned short)(r >> 16);
}

__device__ __forceinline__ short8 pack8(float4 a, float4 b) {
    short8 r;
    r[0] = (short)f2bf(a.x); r[1] = (short)f2bf(a.y);
    r[2] = (short)f2bf(a.z); r[3] = (short)f2bf(a.w);
    r[4] = (short)f2bf(b.x); r[5] = (short)f2bf(b.y);
    r[6] = (short)f2bf(b.z); r[7] = (short)f2bf(b.w);
    return r;
}

// ---- prep: c2 exact fp32 + codebook -> bf16; 4 rows/wave for ILP
__global__ void prep_kernel(const float* __restrict__ cb, float* __restrict__ c2,
                            unsigned short* __restrict__ cbb) {
    const int wave = threadIdx.x >> 6, lane = threadIdx.x & 63;
    const int row0 = blockIdx.x * 16 + wave * 4;
    float4 v4[4];
    float s[4];
    #pragma unroll
    for (int j = 0; j < 4; ++j) {
        v4[j] = *(const float4*)(cb + (size_t)(row0 + j) * D_ + lane * 4);
        s[j] = v4[j].x * v4[j].x + v4[j].y * v4[j].y
             + v4[j].z * v4[j].z + v4[j].w * v4[j].w;
    }
    #pragma unroll
    for (int off = 32; off; off >>= 1) {
        #pragma unroll
        for (int j = 0; j < 4; ++j) s[j] += __shfl_down(s[j], off, 64);
    }
    if (lane == 0) {
        #pragma unroll
        for (int j = 0; j < 4; ++j) c2[row0 + j] = s[j];
    }
    #pragma unroll
    for (int j = 0; j < 4; ++j) {
        ushort4 b4;
        b4.x = f2bf(v4[j].x); b4.y = f2bf(v4[j].y);
        b4.z = f2bf(v4[j].z); b4.w = f2bf(v4[j].w);
        *(ushort4*)(cbb + (size_t)(row0 + j) * D_ + lane * 4) = b4;
    }
}

// ---- fallback prep when ws too small: c2 only
__global__ void c2_kernel(const float* __restrict__ cb, float* __restrict__ c2) {
    const int row = blockIdx.x * 4 + (threadIdx.x >> 6);
    const int lane = threadIdx.x & 63;
    const float4 v = ((const float4*)(cb + (size_t)row * D_))[lane];
    float s = v.x * v.x + v.y * v.y + v.z * v.z + v.w * v.w;
    #pragma unroll
    for (int off = 32; off; off >>= 1) s += __shfl_down(s, off, 64);
    if (lane == 0) c2[row] = s;
}

// ---------------- main: MFMA sweep + candidate collect ----------------
template<int USE_BF>
__global__ __launch_bounds__(256, 2)
void main_kernel(const float* __restrict__ x, const float* __restrict__ cb,
                 const float* __restrict__ c2, const unsigned short* __restrict__ cbb,
                 float* __restrict__ out) {
    const int t  = blockIdx.x;
    const int b0 = blockIdx.y * BT;

    __shared__ short8 A_lds[BT * 32];          // 64 rows x 32 granules, XOR(r&15)
    __shared__ float  minPart4[BT][4];         // per-row per-wave running min
    __shared__ unsigned rowCnt[BT];
    __shared__ unsigned short rowCand[BT * CAP];

    const int tid = threadIdx.x;
    const int w = tid >> 6, lane = tid & 63;
    const int q = lane >> 4, ln = lane & 15;

    if (tid < BT) rowCnt[tid] = 0;
    ((float*)minPart4)[tid] = 3.4e38f;         // 256 = BT*4 exactly

    const unsigned short* bb = cbb + ((size_t)t * V_ + w * 64 + ln) * D_ + q * 8;
    const float*          fb = cb  + ((size_t)t * V_ + w * 64 + ln) * D_ + q * 8;

    auto loadB = [&](int vt, int kc, short8 (&dst)[4]) {
        #pragma unroll
        for (int nt = 0; nt < 4; ++nt) {
            const int off = (vt * VTILE + nt * 16) * D_ + kc * 32;
            if constexpr (USE_BF) {
                dst[nt] = *(const short8*)(bb + off);
            } else {
                const float4* s = (const float4*)(fb + off);
                dst[nt] = pack8(s[0], s[1]);
            }
        }
    };

    // depth-4 ring: issue steps 0,1,2 before the A-stage VALU work (overlap)
    short8 bufs[4][4];
    loadB(0, 0, bufs[0]);
    loadB(0, 1, bufs[1]);
    loadB(0, 2, bufs[2]);

    #pragma unroll
    for (int i = 0; i < 8; ++i) {
        int gid = i * 256 + tid, r = gid >> 5, g = gid & 31;
        const float4* src = (const float4*)(x + (((size_t)(b0 + r)) * T_ + t) * D_ + g * 8);
        A_lds[r * 32 + (g ^ (r & 15))] = pack8(src[0], src[1]);
    }
    __syncthreads();                 // A_lds writes + inits visible

    for (int vt = 0; vt < NVT; ++vt) {
        f32x4 acc[4][4];
        #pragma unroll
        for (int mt = 0; mt < 4; ++mt)
            #pragma unroll
            for (int nt = 0; nt < 4; ++nt) acc[mt][nt] = (f32x4){0.f, 0.f, 0.f, 0.f};

        #pragma unroll
        for (int kc = 0; kc < 8; ++kc) {
            // issue global step gs+3 into ring slot (kc+3)&3 (all compile-time)
            if (!(vt == NVT - 1 && kc >= 5)) {
                loadB(vt + ((kc + 3) >> 3), (kc + 3) & 7, bufs[(kc + 3) & 3]);
            }
            short8 af[4];
            #pragma unroll
            for (int mt = 0; mt < 4; ++mt)
                af[mt] = A_lds[(mt * 16 + ln) * 32 + ((kc * 4 + q) ^ ln)];
            #pragma unroll
            for (int mt = 0; mt < 4; ++mt)
                #pragma unroll
                for (int nt = 0; nt < 4; ++nt)
                    acc[mt][nt] = __builtin_amdgcn_mfma_f32_16x16x32_bf16(
                        af[mt], bufs[kc & 3][nt], acc[mt][nt], 0, 0, 0);
        }

        const float* c2p = c2 + t * V_ + vt * VTILE + w * 64 + ln;
        float cc[4];
        #pragma unroll
        for (int nt = 0; nt < 4; ++nt) cc[nt] = c2p[nt * 16];

        #pragma unroll
        for (int mt = 0; mt < 4; ++mt)
            #pragma unroll
            for (int i = 0; i < 4; ++i) {
                float mn = 3.4e38f;
                #pragma unroll
                for (int nt = 0; nt < 4; ++nt)
                    mn = fminf(mn, fmaf(-2.0f, acc[mt][nt][i], cc[nt]));
                mn = fminf(mn, __shfl_xor(mn, 1, 64));
                mn = fminf(mn, __shfl_xor(mn, 2, 64));
                mn = fminf(mn, __shfl_xor(mn, 4, 64));
                mn = fminf(mn, __shfl_xor(mn, 8, 64));
                if (ln == 0) {
                    const int r = mt * 16 + q * 4 + i;
                    minPart4[r][w] = fminf(minPart4[r][w], mn);
                }
            }
        __syncthreads();   // this vt's 4-wave mins visible

        #pragma unroll
        for (int mt = 0; mt < 4; ++mt)
            #pragma unroll
            for (int i = 0; i < 4; ++i) {
                const int r = mt * 16 + q * 4 + i;
                const float4 mp = *(const float4*)minPart4[r];
                const float thr = fminf(fminf(mp.x, mp.y), fminf(mp.z, mp.w)) + MARGIN;
                #pragma unroll
                for (int nt = 0; nt < 4; ++nt) {
                    float s = fmaf(-2.0f, acc[mt][nt][i], cc[nt]);
                    if (s < thr) {
                        unsigned pos = atomicAdd(&rowCnt[r], 1u);
                        if (pos < CAP)
                            rowCand[r * CAP + pos] =
                                (unsigned short)(vt * VTILE + w * 64 + nt * 16 + ln);
                    }
                }
            }
        // DETERMINISM BARRIER (R8 fix): collect(vt) must see exactly mins
        // through vt; without this a fast wave's next-vt update races.
        __syncthreads();
    }

    // ---- dump cnt + cand list into the row's own embed slot (finish overwrites)
    if (tid < BT) {
        const int r = tid;
        unsigned* slot = (unsigned*)(out + (((size_t)(b0 + r)) * T_ + t) * D_);
        slot[0] = rowCnt[r];
        const unsigned short* rc = &rowCand[r * CAP];
        #pragma unroll
        for (int k = 0; k < CAP / 2; ++k)
            slot[1 + k] = (unsigned)rc[2 * k] | ((unsigned)rc[2 * k + 1] << 16);
    }
}

// ---------------- finish: exact fp32 rescore + idx + gather ----------------
__global__ __launch_bounds__(256, 4)
void finish_kernel(const float* __restrict__ x, const float* __restrict__ cb,
                   const float* __restrict__ c2, float* __restrict__ out) {
    const int t = blockIdx.x;
    const int b = blockIdx.y * 16 + (threadIdx.x >> 4);   // one row per 16-lane group
    const int l16 = threadIdx.x & 15;

    float* slot = out + ((size_t)b * T_ + t) * D_;
    const unsigned cnt = ((const unsigned*)slot)[0];

    const float* xp = x + ((size_t)b * T_ + t) * D_ + l16 * 16;
    float4 xr[4];
    #pragma unroll
    for (int k = 0; k < 4; ++k) xr[k] = ((const float4*)xp)[k];

    const float* cbt = cb + (size_t)t * V_ * D_ + l16 * 16;
    const float* c2t = c2 + t * V_;

    auto dot16 = [&](int v) {   // partial dot over this lane's 16 elems
        const float* cr = cbt + (size_t)v * D_;
        float d = 0.f;
        #pragma unroll
        for (int k = 0; k < 4; ++k) {
            float4 bv = ((const float4*)cr)[k];
            d = fmaf(xr[k].x, bv.x, d); d = fmaf(xr[k].y, bv.y, d);
            d = fmaf(xr[k].z, bv.z, d); d = fmaf(xr[k].w, bv.w, d);
        }
        return d;
    };
    auto reduce16 = [&](float d) {
        d += __shfl_xor(d, 1, 64);
        d += __shfl_xor(d, 2, 64);
        d += __shfl_xor(d, 4, 64);
        d += __shfl_xor(d, 8, 64);
        return d;
    };
    unsigned long long best = ~0ULL;
    auto merge = [&](float dot, int v) {
        float sc = fmaf(-2.0f, dot, c2t[v]);
        unsigned u = __builtin_bit_cast(unsigned, sc);
        u = (u & 0x80000000u) ? ~u : (u | 0x80000000u);   // sortable fp32
        unsigned long long e = ((unsigned long long)u << 32) | (unsigned)v;
        if (e < best) best = e;
    };

    if (cnt <= CAP) {
        unsigned c = 0;
        for (; c + 2 <= cnt; c += 2) {          // 2-way ILP (pairs are one uint)
            unsigned pr = ((const unsigned*)slot)[1 + (c >> 1)];
            const int v0 = (int)(pr & 0xffffu), v1 = (int)(pr >> 16);
            float d0 = dot16(v0), d1 = dot16(v1);
            d0 = reduce16(d0); d1 = reduce16(d1);
            merge(d0, v0); merge(d1, v1);
        }
        if (c < cnt) {
            unsigned pr = ((const unsigned*)slot)[1 + (c >> 1)];
            const int v0 = (int)(pr & 0xffffu);
            merge(reduce16(dot16(v0)), v0);
        }
    } else {
        for (int v = 0; v < V_; v += 4) {       // overflow fallback, 4-way ILP
            float d0 = dot16(v),     d1 = dot16(v + 1);
            float d2 = dot16(v + 2), d3 = dot16(v + 3);
            d0 = reduce16(d0); d1 = reduce16(d1);
            d2 = reduce16(d2); d3 = reduce16(d3);
            merge(d0, v); merge(d1, v + 1); merge(d2, v + 2); merge(d3, v + 3);
        }
    }

    // all 16 lanes hold identical best (uniform loop + full 16-lane reduce)
    const int idx = (int)(best & 1023u);
    if (l16 == 0) out[(size_t)B_ * T_ * D_ + (size_t)b * T_ + t] = (float)idx;

    // gather: overwrite slot with codebook row (reads of slot are done above)
    const float* cr = cb + ((size_t)t * V_ + idx) * D_;
    #pragma unroll
    for (int k = 0; k < 4; ++k)
        *(float4*)(slot + k * 64 + l16 * 4) = *(const float4*)(cr + k * 64 + l16 * 4);
}

extern "C" void kernel_launch(void* const* d_in, const int* in_sizes, int n_in,
                              void* d_out, int out_size, void* d_ws, size_t ws_size,
                              hipStream_t stream) {
    const float* x  = (const float*)d_in[0];   // (B,T,D)
    const float* cb = (const float*)d_in[1];   // (T,V,D)
    float* out = (float*)d_out;                // embed fp32 ++ idx (as float)
    float* c2  = (float*)d_ws;                 // 32768 floats = 128 KB
    unsigned short* cbb = (unsigned short*)((char*)d_ws + 131072);  // 16 MB bf16 codebook
    const size_t NEED = 131072 + (size_t)T_ * V_ * D_ * 2;
    const int use_bf = (ws_size >= NEED) ? 1 : 0;

    if (use_bf) {
        prep_kernel<<<dim3(T_ * V_ / 16), 256, 0, stream>>>(cb, c2, cbb);
        main_kernel<1><<<dim3(T_, B_ / BT), 256, 0, stream>>>(x, cb, c2, cbb, out);
    } else {
        c2_kernel<<<dim3(T_ * V_ / 4), 256, 0, stream>>>(cb, c2);
        main_kernel<0><<<dim3(T_, B_ / BT), 256, 0, stream>>>(x, cb, c2, cbb, out);
    }
    finish_kernel<<<dim3(T_, B_ / 16), 256, 0, stream>>>(x, cb, c2, out);
}